// Round 3
// baseline (146.249 us; speedup 1.0000x reference)
//
#include <hip/hip_runtime.h>
#include <math.h>

#define NB    2
#define NPTS  65536
#define NVSUB 689
#define NJ    24
#define GR    64
#define GRV   (GR*GR*GR)          // 262144 voxels
#define THRESH2 0.0144f           // 0.12^2

// output layout (floats): pts_cano [B,N,1,3] | mask [B,N,1] | w_tf [B,N,4,4]
#define O_PTS  0
#define O_MASK (NB*NPTS*3)        // 393216
#define O_WTF  (O_MASK + NB*NPTS) // 524288

// ws layout: gT [GRV][24] f32 | vs4 [689] float4
#define WS_VS4_OFF (GRV * NJ)     // in floats

// ---------------- prep: transpose grid + build vs4 table ----------------
__global__ __launch_bounds__(256) void prep_kernel(const float* __restrict__ g,
                                                   const float* __restrict__ vs,
                                                   float* __restrict__ ws) {
    if (blockIdx.x < GRV / 256) {
        int vox = blockIdx.x * 256 + threadIdx.x;
        float v[NJ];
#pragma unroll
        for (int c = 0; c < NJ; ++c) v[c] = g[c * GRV + vox];   // coalesced per c
        float4* dst = (float4*)(ws + (size_t)vox * NJ);
#pragma unroll
        for (int c4 = 0; c4 < 6; ++c4)
            dst[c4] = make_float4(v[4*c4+0], v[4*c4+1], v[4*c4+2], v[4*c4+3]);
    } else {
        float4* vs4 = (float4*)(ws + WS_VS4_OFF);
        for (int i = threadIdx.x; i < NVSUB; i += 256) {
            float x = vs[i * 3 + 0], y = vs[i * 3 + 1], z = vs[i * 3 + 2];
            vs4[i] = make_float4(x, y, z, x * x + y * y + z * z);
        }
    }
}

// ---------------- main fused kernel ----------------
// Block = 256 threads = 4 waves, handles 64 points (both batches).
// Phase 1 (KNN): wave q scans vertex quarter q for BOTH batches; vertices come
//   from the uniform vs4 table via scalar loads (no LDS).  Partial mins -> s_m.
// Phase 2: wave q -> batch b=q&1, joint-half half=q>>1 (channels 12h..12h+11).
//   Each thread: trilinear over its 12 channels (3 float4 loads/corner) +
//   partial skinning acc[16] with tfs rows via uniform scalar loads.
//   half=1 writes partials to LDS; half=0 merges, normalizes, stores outputs.
__global__ __launch_bounds__(256, 4) void snarf_main(
    const float* __restrict__ pts_in,    // [2,N,3]
    const float* __restrict__ shape_off, // [6890,3]
    const int*   __restrict__ init_idx,  // [N,3]
    const float* __restrict__ init_bar,  // [N,3]
    const float* __restrict__ ws,        // gT + vs4
    const float* __restrict__ tfs,       // [2,24,4,4]
    const float* __restrict__ gscale,    // [3]
    const float* __restrict__ goff,      // [3]
    float* __restrict__ out) {
    __shared__ float s_m[NB][4][64];
    __shared__ float s_part[NB][64][20];   // 16 acc + wsum (stride 20 for 16B align)

    const int tid  = threadIdx.x;
    const int q    = tid >> 6;
    const int nl   = tid & 63;
    const int b    = q & 1;
    const int half = q >> 1;
    const int n    = blockIdx.x * 64 + nl;

    const float4* vs4 = (const float4*)(ws + WS_VS4_OFF);
    const float*  gT  = ws;

    const float p0x = pts_in[n * 3 + 0], p0y = pts_in[n * 3 + 1], p0z = pts_in[n * 3 + 2];
    const float p1x = pts_in[(NPTS + n) * 3 + 0], p1y = pts_in[(NPTS + n) * 3 + 1],
                p1z = pts_in[(NPTS + n) * 3 + 2];

    // ---- phase 1: KNN over this wave's vertex quarter ----
    const int vbeg = q * 172 + (q != 0);          // 0,173,345,517
    const int vend = (q + 1) * 172 + 1;           // 173,345,517,689
    float m0a = 3.4e38f, m0b = 3.4e38f, m1a = 3.4e38f, m1b = 3.4e38f;
    int v = vbeg;
    for (; v + 4 <= vend; v += 4) {
        float4 t0 = vs4[v], t1 = vs4[v + 1], t2 = vs4[v + 2], t3 = vs4[v + 3];
        m0a = fminf(m0a, fmaf(-2.f, p0x * t0.x + p0y * t0.y + p0z * t0.z, t0.w));
        m1a = fminf(m1a, fmaf(-2.f, p1x * t0.x + p1y * t0.y + p1z * t0.z, t0.w));
        m0b = fminf(m0b, fmaf(-2.f, p0x * t1.x + p0y * t1.y + p0z * t1.z, t1.w));
        m1b = fminf(m1b, fmaf(-2.f, p1x * t1.x + p1y * t1.y + p1z * t1.z, t1.w));
        m0a = fminf(m0a, fmaf(-2.f, p0x * t2.x + p0y * t2.y + p0z * t2.z, t2.w));
        m1a = fminf(m1a, fmaf(-2.f, p1x * t2.x + p1y * t2.y + p1z * t2.z, t2.w));
        m0b = fminf(m0b, fmaf(-2.f, p0x * t3.x + p0y * t3.y + p0z * t3.z, t3.w));
        m1b = fminf(m1b, fmaf(-2.f, p1x * t3.x + p1y * t3.y + p1z * t3.z, t3.w));
    }
    for (; v < vend; ++v) {
        float4 t0 = vs4[v];
        m0a = fminf(m0a, fmaf(-2.f, p0x * t0.x + p0y * t0.y + p0z * t0.z, t0.w));
        m1a = fminf(m1a, fmaf(-2.f, p1x * t0.x + p1y * t0.y + p1z * t0.z, t0.w));
    }
    s_m[0][q][nl] = fminf(m0a, m0b);
    s_m[1][q][nl] = fminf(m1a, m1b);
    __syncthreads();

    // ---- phase 2 (all waves) ----
    // barycentric shape offset (same for both b)
    int i0 = init_idx[n * 3 + 0] * 3;
    int i1 = init_idx[n * 3 + 1] * 3;
    int i2 = init_idx[n * 3 + 2] * 3;
    float b0 = init_bar[n * 3 + 0], b1 = init_bar[n * 3 + 1], b2 = init_bar[n * 3 + 2];
    float ox = b0 * shape_off[i0 + 0] + b1 * shape_off[i1 + 0] + b2 * shape_off[i2 + 0];
    float oy = b0 * shape_off[i0 + 1] + b1 * shape_off[i1 + 1] + b2 * shape_off[i2 + 1];
    float oz = b0 * shape_off[i0 + 2] + b1 * shape_off[i1 + 2] + b2 * shape_off[i2 + 2];

    const float qx = (b ? p1x : p0x) + ox;
    const float qy = (b ? p1y : p0y) + oy;
    const float qz = (b ? p1z : p0z) + oz;

    float cx = fminf(fmaxf((qx - goff[0]) * gscale[0], -1.f), 1.f);
    float cy = fminf(fmaxf((qy - goff[1]) * gscale[1], -1.f), 1.f);
    float cz = fminf(fmaxf((qz - goff[2]) * gscale[2], -1.f), 1.f);
    float x = (cx + 1.f) * 0.5f * (GR - 1);
    float y = (cy + 1.f) * 0.5f * (GR - 1);
    float z = (cz + 1.f) * 0.5f * (GR - 1);
    int x0 = (int)floorf(x), y0 = (int)floorf(y), z0 = (int)floorf(z);
    int x1 = min(x0 + 1, GR - 1), y1 = min(y0 + 1, GR - 1), z1 = min(z0 + 1, GR - 1);
    float fx = x - (float)x0, fy = y - (float)y0, fz = z - (float)z0;
    float wx[2] = {1.f - fx, fx}, wy[2] = {1.f - fy, fy}, wz[2] = {1.f - fz, fz};

    const int jbeg = half * 12;
    float w[12];
#pragma unroll
    for (int c = 0; c < 12; ++c) w[c] = 0.f;

#pragma unroll
    for (int ci = 0; ci < 8; ++ci) {
        int xi = (ci & 1) ? x1 : x0;
        int yi = (ci & 2) ? y1 : y0;
        int zi = (ci & 4) ? z1 : z0;
        float wt = wx[ci & 1] * wy[(ci >> 1) & 1] * wz[(ci >> 2) & 1];
        int vox = (zi * GR + yi) * GR + xi;
        const float4* g4 = (const float4*)(gT + (size_t)vox * NJ + jbeg);
        float4 g0 = g4[0], g1 = g4[1], g2 = g4[2];
        w[0]  = fmaf(wt, g0.x, w[0]);  w[1]  = fmaf(wt, g0.y, w[1]);
        w[2]  = fmaf(wt, g0.z, w[2]);  w[3]  = fmaf(wt, g0.w, w[3]);
        w[4]  = fmaf(wt, g1.x, w[4]);  w[5]  = fmaf(wt, g1.y, w[5]);
        w[6]  = fmaf(wt, g1.z, w[6]);  w[7]  = fmaf(wt, g1.w, w[7]);
        w[8]  = fmaf(wt, g2.x, w[8]);  w[9]  = fmaf(wt, g2.y, w[9]);
        w[10] = fmaf(wt, g2.z, w[10]); w[11] = fmaf(wt, g2.w, w[11]);
    }
    float wsum = 0.f;
#pragma unroll
    for (int c = 0; c < 12; ++c) wsum += w[c];

    // partial skinning: acc[k] = sum_j w[j] * tfs[b][jbeg+j][k]  (unnormalized)
    const int bu = __builtin_amdgcn_readfirstlane(b);
    const int jbu = __builtin_amdgcn_readfirstlane(jbeg);
    const float* tb = tfs + (size_t)(bu * NJ + jbu) * 16;
    float acc[16];
#pragma unroll
    for (int k = 0; k < 16; ++k) acc[k] = 0.f;
#pragma unroll
    for (int jj = 0; jj < 12; ++jj) {
        float wj = w[jj];
#pragma unroll
        for (int k = 0; k < 16; ++k) acc[k] = fmaf(wj, tb[jj * 16 + k], acc[k]);
    }

    if (half == 1) {
        float* sp = &s_part[b][nl][0];
        ((float4*)sp)[0] = make_float4(acc[0],  acc[1],  acc[2],  acc[3]);
        ((float4*)sp)[1] = make_float4(acc[4],  acc[5],  acc[6],  acc[7]);
        ((float4*)sp)[2] = make_float4(acc[8],  acc[9],  acc[10], acc[11]);
        ((float4*)sp)[3] = make_float4(acc[12], acc[13], acc[14], acc[15]);
        sp[16] = wsum;
    }
    __syncthreads();

    if (half == 0) {
        const float* sp = &s_part[b][nl][0];
        float4 q0 = ((const float4*)sp)[0], q1 = ((const float4*)sp)[1];
        float4 q2 = ((const float4*)sp)[2], q3 = ((const float4*)sp)[3];
        acc[0] += q0.x;  acc[1] += q0.y;  acc[2] += q0.z;  acc[3] += q0.w;
        acc[4] += q1.x;  acc[5] += q1.y;  acc[6] += q1.z;  acc[7] += q1.w;
        acc[8] += q2.x;  acc[9] += q2.y;  acc[10] += q2.z; acc[11] += q2.w;
        acc[12] += q3.x; acc[13] += q3.y; acc[14] += q3.z; acc[15] += q3.w;
        wsum += sp[16];
        float inv = __builtin_amdgcn_rcpf(fmaxf(wsum, 1e-6f));
#pragma unroll
        for (int k = 0; k < 16; ++k) acc[k] *= inv;

        float px = acc[0] * qx + acc[1] * qy + acc[2]  * qz + acc[3];
        float py = acc[4] * qx + acc[5] * qy + acc[6]  * qz + acc[7];
        float pz = acc[8] * qx + acc[9] * qy + acc[10] * qz + acc[11];

        float mm = fminf(fminf(s_m[b][0][nl], s_m[b][1][nl]),
                         fminf(s_m[b][2][nl], s_m[b][3][nl]));
        float pbx = b ? p1x : p0x, pby = b ? p1y : p0y, pbz = b ? p1z : p0z;
        float dist2 = mm + pbx * pbx + pby * pby + pbz * pbz;

        size_t bn = (size_t)b * NPTS + n;
        out[O_PTS + bn * 3 + 0] = px;
        out[O_PTS + bn * 3 + 1] = py;
        out[O_PTS + bn * 3 + 2] = pz;
        out[O_MASK + bn] = (dist2 < THRESH2) ? 1.f : 0.f;
        float4* wt4 = (float4*)(out + O_WTF + bn * 16);
        wt4[0] = make_float4(acc[0],  acc[1],  acc[2],  acc[3]);
        wt4[1] = make_float4(acc[4],  acc[5],  acc[6],  acc[7]);
        wt4[2] = make_float4(acc[8],  acc[9],  acc[10], acc[11]);
        wt4[3] = make_float4(acc[12], acc[13], acc[14], acc[15]);
    }
}

// ---------------- fallback (ws too small): round-0 style, raw grid ----------------
__global__ __launch_bounds__(256) void snarf_fallback(
    const float* __restrict__ pts_in, const float* __restrict__ vs,
    const float* __restrict__ shape_off, const int* __restrict__ init_idx,
    const float* __restrict__ init_bar, const float* __restrict__ grid,
    const float* __restrict__ tfs, const float* __restrict__ gscale,
    const float* __restrict__ goff, float* __restrict__ out) {
    const int n = blockIdx.x * 256 + threadIdx.x;
    for (int b = 0; b < NB; ++b) {
        float px = pts_in[((size_t)b * NPTS + n) * 3 + 0];
        float py = pts_in[((size_t)b * NPTS + n) * 3 + 1];
        float pz = pts_in[((size_t)b * NPTS + n) * 3 + 2];
        float mm = 3.4e38f;
        for (int v = 0; v < NVSUB; ++v) {
            float dx = px - vs[v * 3 + 0], dy = py - vs[v * 3 + 1], dz = pz - vs[v * 3 + 2];
            mm = fminf(mm, dx * dx + dy * dy + dz * dz);
        }
        int i0 = init_idx[n * 3 + 0] * 3, i1 = init_idx[n * 3 + 1] * 3, i2 = init_idx[n * 3 + 2] * 3;
        float b0 = init_bar[n * 3 + 0], b1 = init_bar[n * 3 + 1], b2 = init_bar[n * 3 + 2];
        float qx = px + b0 * shape_off[i0 + 0] + b1 * shape_off[i1 + 0] + b2 * shape_off[i2 + 0];
        float qy = py + b0 * shape_off[i0 + 1] + b1 * shape_off[i1 + 1] + b2 * shape_off[i2 + 1];
        float qz = pz + b0 * shape_off[i0 + 2] + b1 * shape_off[i1 + 2] + b2 * shape_off[i2 + 2];
        float cx = fminf(fmaxf((qx - goff[0]) * gscale[0], -1.f), 1.f);
        float cy = fminf(fmaxf((qy - goff[1]) * gscale[1], -1.f), 1.f);
        float cz = fminf(fmaxf((qz - goff[2]) * gscale[2], -1.f), 1.f);
        float x = (cx + 1.f) * 0.5f * (GR - 1), y = (cy + 1.f) * 0.5f * (GR - 1), z = (cz + 1.f) * 0.5f * (GR - 1);
        int x0 = (int)floorf(x), y0 = (int)floorf(y), z0 = (int)floorf(z);
        int x1 = min(x0 + 1, GR - 1), y1 = min(y0 + 1, GR - 1), z1 = min(z0 + 1, GR - 1);
        float fx = x - x0, fy = y - y0, fz = z - z0;
        float wxa[2] = {1.f - fx, fx}, wya[2] = {1.f - fy, fy}, wza[2] = {1.f - fz, fz};
        float w[NJ];
        for (int c = 0; c < NJ; ++c) w[c] = 0.f;
        for (int ci = 0; ci < 8; ++ci) {
            int xi = (ci & 1) ? x1 : x0, yi = (ci & 2) ? y1 : y0, zi = (ci & 4) ? z1 : z0;
            float wt = wxa[ci & 1] * wya[(ci >> 1) & 1] * wza[(ci >> 2) & 1];
            int vox = (zi * GR + yi) * GR + xi;
            for (int c = 0; c < NJ; ++c) w[c] = fmaf(wt, grid[c * GRV + vox], w[c]);
        }
        float s = 0.f;
        for (int c = 0; c < NJ; ++c) s += w[c];
        float inv = 1.f / fmaxf(s, 1e-6f);
        float acc[16];
        for (int k = 0; k < 16; ++k) acc[k] = 0.f;
        for (int j = 0; j < NJ; ++j) {
            float wj = w[j] * inv;
            for (int k = 0; k < 16; ++k) acc[k] = fmaf(wj, tfs[(b * NJ + j) * 16 + k], acc[k]);
        }
        size_t bn = (size_t)b * NPTS + n;
        out[O_PTS + bn * 3 + 0] = acc[0] * qx + acc[1] * qy + acc[2] * qz + acc[3];
        out[O_PTS + bn * 3 + 1] = acc[4] * qx + acc[5] * qy + acc[6] * qz + acc[7];
        out[O_PTS + bn * 3 + 2] = acc[8] * qx + acc[9] * qy + acc[10] * qz + acc[11];
        out[O_MASK + bn] = (mm < THRESH2) ? 1.f : 0.f;
        for (int k = 0; k < 16; ++k) out[O_WTF + bn * 16 + k] = acc[k];
    }
}

extern "C" void kernel_launch(void* const* d_in, const int* in_sizes, int n_in,
                              void* d_out, int out_size, void* d_ws, size_t ws_size,
                              hipStream_t stream) {
    const float* pts_in    = (const float*)d_in[0];
    const float* vs        = (const float*)d_in[1];
    const float* shape_off = (const float*)d_in[2];
    const int*   init_idx  = (const int*)d_in[3];
    const float* init_bar  = (const float*)d_in[4];
    const float* lbs       = (const float*)d_in[5];
    const float* tfs       = (const float*)d_in[6];
    const float* gs        = (const float*)d_in[7];
    const float* go        = (const float*)d_in[8];
    float* out = (float*)d_out;

    const size_t needed = ((size_t)GRV * NJ + NVSUB * 4) * sizeof(float);  // ~25.2 MB
    if (ws_size >= needed) {
        float* wsf = (float*)d_ws;
        prep_kernel<<<GRV / 256 + 1, 256, 0, stream>>>(lbs, vs, wsf);
        snarf_main<<<NPTS / 64, 256, 0, stream>>>(
            pts_in, shape_off, init_idx, init_bar, wsf, tfs, gs, go, out);
    } else {
        snarf_fallback<<<NPTS / 256, 256, 0, stream>>>(
            pts_in, vs, shape_off, init_idx, init_bar, lbs, tfs, gs, go, out);
    }
}